// Round 1
// baseline (2442.967 us; speedup 1.0000x reference)
//
#include <hip/hip_runtime.h>
#include <math.h>

#define Bx 8
#define IMG 128
#define DD 128
#define HEADS 4
#define LL 2
#define PCc 8
#define PFf 4
#define HCc 16
#define NCc 256
#define HFf 32
#define NFf 1024
#define NTOK 1280
#define HD 32

// ---------------- coarse patch embed: tokens[:, :256] = patch@Wpc + bpc + te[0]
__global__ __launch_bounds__(128) void k_coarse(const float* __restrict__ x,
    const float* __restrict__ Wpc, const float* __restrict__ bpc,
    const float* __restrict__ te, float* __restrict__ tokens) {
  int blk = blockIdx.x;            // b*NC + t
  int b = blk / NCc, t = blk % NCc;
  int hc = t / HCc, wc = t % HCc;
  int d = threadIdx.x;
  __shared__ float patch[PCc * PCc];
  if (d < PCc * PCc) {
    int pi = d / PCc, pj = d % PCc;
    patch[d] = x[(b * IMG + hc * PCc + pi) * IMG + wc * PCc + pj];
  }
  __syncthreads();
  float acc = bpc[d] + te[d];
  #pragma unroll 8
  for (int i = 0; i < PCc * PCc; ++i) acc += patch[i] * Wpc[i * DD + d];
  tokens[(size_t)(b * NTOK + t) * DD + d] = acc;
}

// ---------------- fine patch embed -> fine buffer [B,NF,D]
__global__ __launch_bounds__(128) void k_fine(const float* __restrict__ x,
    const float* __restrict__ Wpf, const float* __restrict__ bpf,
    float* __restrict__ fineb) {
  int blk = blockIdx.x;            // b*NF + t
  int b = blk / NFf, t = blk % NFf;
  int hf = t / HFf, wf = t % HFf;
  int d = threadIdx.x;
  __shared__ float patch[PFf * PFf];
  if (d < PFf * PFf) {
    int pi = d / PFf, pj = d % PFf;
    patch[d] = x[(b * IMG + hf * PFf + pi) * IMG + wf * PFf + pj];
  }
  __syncthreads();
  float acc = bpf[d];
  #pragma unroll
  for (int i = 0; i < PFf * PFf; ++i) acc += patch[i] * Wpf[i * DD + d];
  fineb[(size_t)(b * NFf + t) * DD + d] = acc;
}

// ---------------- sobel -> avgpool4 -> mask -> stable sort (prefix-sum) per image
__global__ __launch_bounds__(1024) void k_edge_sort(const float* __restrict__ x,
    int* __restrict__ order, float* __restrict__ msort) {
  int b = blockIdx.x;
  int t = threadIdx.x;             // 0..1023 -> fine cell (fy,fx)
  int fy = t >> 5, fx = t & 31;
  const float* img = x + (size_t)b * IMG * IMG;
  float s = 0.f;
  for (int dy = 0; dy < 4; ++dy) {
    for (int dx = 0; dx < 4; ++dx) {
      int py = fy * 4 + dy, px = fx * 4 + dx;
      float v[3][3];
      #pragma unroll
      for (int ky = 0; ky < 3; ++ky)
        #pragma unroll
        for (int kx = 0; kx < 3; ++kx) {
          int yy = py + ky - 1, xx = px + kx - 1;
          v[ky][kx] = (yy >= 0 && yy < IMG && xx >= 0 && xx < IMG)
                          ? img[yy * IMG + xx] : 0.f;
        }
      float gx = -v[0][0] + v[0][2] - 2.f * v[1][0] + 2.f * v[1][2] - v[2][0] + v[2][2];
      float gy = -v[0][0] - 2.f * v[0][1] - v[0][2] + v[2][0] + 2.f * v[2][1] + v[2][2];
      s += sqrtf(gx * gx + gy * gy);
    }
  }
  float e = s * (1.f / 16.f);
  __shared__ float red[1024];
  red[t] = e;
  __syncthreads();
  for (int off = 512; off > 0; off >>= 1) {
    if (t < off) red[t] += red[t + off];
    __syncthreads();
  }
  float mean = red[0] * (1.f / 1024.f);
  int m = (e > mean) ? 1 : 0;
  __shared__ int ps[1024];
  ps[t] = m;
  __syncthreads();
  for (int off = 1; off < 1024; off <<= 1) {
    int v2 = (t >= off) ? ps[t - off] : 0;
    __syncthreads();
    ps[t] += v2;
    __syncthreads();
  }
  int total = ps[1023];
  int incl = ps[t];
  int excl = incl - m;
  int pos = m ? excl : (total + t - excl);
  order[b * NFf + pos] = t;
  msort[b * NFf + pos] = (float)m;
}

// ---------------- gather fine tokens into tokens[:, 256:]
__global__ __launch_bounds__(128) void k_fine_tokens(const float* __restrict__ fineb,
    const int* __restrict__ order, const float* __restrict__ msort,
    const float* __restrict__ te, float* __restrict__ tokens) {
  int blk = blockIdx.x;            // b*NF + j
  int b = blk / NFf, j = blk % NFf;
  int d = threadIdx.x;
  int src = order[b * NFf + j];
  float v = fineb[(size_t)(b * NFf + src) * DD + d] * msort[b * NFf + j] + te[DD + d];
  tokens[(size_t)(b * NTOK + NCc + j) * DD + d] = v;
}

// ---------------- LayerNorm over D=128, one block per row
__global__ __launch_bounds__(128) void k_ln(const float* __restrict__ inp,
    const float* __restrict__ g, const float* __restrict__ bb,
    float* __restrict__ outp) {
  int row = blockIdx.x;
  int d = threadIdx.x;
  float v = inp[(size_t)row * DD + d];
  __shared__ float red[DD];
  red[d] = v;
  __syncthreads();
  for (int off = 64; off > 0; off >>= 1) {
    if (d < off) red[d] += red[d + off];
    __syncthreads();
  }
  float mean = red[0] * (1.f / DD);
  __syncthreads();
  float c = v - mean;
  red[d] = c * c;
  __syncthreads();
  for (int off = 64; off > 0; off >>= 1) {
    if (d < off) red[d] += red[d + off];
    __syncthreads();
  }
  float var = red[0] * (1.f / DD);
  outp[(size_t)row * DD + d] = c * rsqrtf(var + 1e-5f) * g[d] + bb[d];
}

// ---------------- generic GEMM: C[M,Nout] = act(A[M,K]@W + bias) (+=C if resid)
// block = 256 threads = 8 rows x 32 cols; dyn-LDS = 8*K floats
__global__ __launch_bounds__(256) void k_gemm(const float* __restrict__ A,
    const float* __restrict__ W, const float* __restrict__ bias,
    float* __restrict__ C, int K, int Nout, int do_gelu, int do_resid) {
  extern __shared__ float Atile[];   // 8*K
  int row0 = blockIdx.x * 8;
  int col0 = blockIdx.y * 32;
  for (int idx = threadIdx.x; idx < 8 * K; idx += 256)
    Atile[idx] = A[(size_t)(row0 + idx / K) * K + (idx % K)];
  __syncthreads();
  int tx = threadIdx.x & 31, ty = threadIdx.x >> 5;
  int col = col0 + tx;
  const float* Arow = Atile + ty * K;
  float acc = 0.f;
  for (int k = 0; k < K; ++k) acc += Arow[k] * W[(size_t)k * Nout + col];
  if (bias) acc += bias[col];
  if (do_gelu) acc = 0.5f * acc * (1.f + erff(acc * 0.70710678118654752f));
  float* op = &C[(size_t)(row0 + ty) * Nout + col];
  if (do_resid) *op += acc; else *op = acc;
}

// ---------------- attention: one wave per (b,h,q); p-row staged in LDS
__global__ __launch_bounds__(256) void k_attn(const float* __restrict__ qkv,
    float* __restrict__ obuf) {
  __shared__ float p[4][NTOK];
  int wave = threadIdx.x >> 6, lane = threadIdx.x & 63;
  int w = blockIdx.x * 4 + wave;
  int q = w % NTOK;
  int h = (w / NTOK) % HEADS;
  int b = w / (NTOK * HEADS);
  const float* qptr = qkv + (size_t)(b * NTOK + q) * 384 + h * HD;
  float4 qv[8];
  const float4* qp4 = (const float4*)qptr;
  #pragma unroll
  for (int i = 0; i < 8; ++i) qv[i] = qp4[i];
  const float scale = 0.17677669529663687f;  // 1/sqrt(32)
  float mymax = -1e30f;
  const float* kbase = qkv + (size_t)b * NTOK * 384 + 128 + h * HD;
  for (int kk = lane; kk < NTOK; kk += 64) {
    const float4* kp4 = (const float4*)(kbase + (size_t)kk * 384);
    float s = 0.f;
    #pragma unroll
    for (int i = 0; i < 8; ++i) {
      float4 kv = kp4[i];
      s += qv[i].x * kv.x + qv[i].y * kv.y + qv[i].z * kv.z + qv[i].w * kv.w;
    }
    s *= scale;
    p[wave][kk] = s;
    mymax = fmaxf(mymax, s);
  }
  #pragma unroll
  for (int off = 32; off > 0; off >>= 1)
    mymax = fmaxf(mymax, __shfl_xor(mymax, off, 64));
  float mysum = 0.f;
  for (int kk = lane; kk < NTOK; kk += 64) {
    float e = __expf(p[wave][kk] - mymax);
    p[wave][kk] = e;
    mysum += e;
  }
  #pragma unroll
  for (int off = 32; off > 0; off >>= 1) mysum += __shfl_xor(mysum, off, 64);
  float rs = 1.f / mysum;
  __syncthreads();   // order LDS p-writes before cross-lane reads (block-uniform)
  int d2 = lane & 31, half = lane >> 5;
  const float* vbase = qkv + (size_t)b * NTOK * 384 + 256 + h * HD + d2;
  float acc = 0.f;
  for (int kk = half * 640; kk < half * 640 + 640; ++kk)
    acc += p[wave][kk] * vbase[(size_t)kk * 384];
  acc += __shfl_down(acc, 32, 64);
  if (half == 0)
    obuf[(size_t)(b * NTOK + q) * DD + h * HD + d2] = acc * rs;
}

// ---------------- coarse decoder head + 16->32 align-corners bilinear
__global__ __launch_bounds__(1024) void k_coarse_dec(const float* __restrict__ tokens,
    const float* __restrict__ dWc, const float* __restrict__ dbc,
    float* __restrict__ c_up) {
  int b = blockIdx.x;
  int t = threadIdx.x;
  __shared__ float c[NCc];
  if (t < NCc) {
    const float* row = tokens + (size_t)(b * NTOK + t) * DD;
    float a = 0.f;
    for (int d = 0; d < DD; ++d) a += row[d] * dWc[d];
    c[t] = a + dbc[0];
  }
  __syncthreads();
  int oy = t >> 5, ox = t & 31;
  float ys = oy * (15.f / 31.f);
  float xs = ox * (15.f / 31.f);
  int y0 = (int)floorf(ys); int y1 = min(y0 + 1, 15); float wy = ys - (float)y0;
  int x0 = (int)floorf(xs); int x1 = min(x0 + 1, 15); float wx = xs - (float)x0;
  float v = c[y0 * 16 + x0] * (1.f - wy) * (1.f - wx)
          + c[y0 * 16 + x1] * (1.f - wy) * wx
          + c[y1 * 16 + x0] * wy * (1.f - wx)
          + c[y1 * 16 + x1] * wy * wx;
  c_up[b * 1024 + t] = v;
}

// ---------------- fine decoder head, mask, scatter back to pixel order
__global__ __launch_bounds__(256) void k_fine_dec(const float* __restrict__ tokens,
    const float* __restrict__ dWf, const float* __restrict__ dbf,
    const float* __restrict__ msort, const int* __restrict__ order,
    float* __restrict__ f_map) {
  int idx = blockIdx.x * 256 + threadIdx.x;  // b*NF + j
  int b = idx >> 10, j = idx & 1023;
  const float* row = tokens + (size_t)(b * NTOK + NCc + j) * DD;
  float a = 0.f;
  for (int d = 0; d < DD; ++d) a += row[d] * dWf[d];
  a = (a + dbf[0]) * msort[b * NFf + j];
  f_map[b * NFf + order[b * NFf + j]] = a;  // 32->32 AC-bilinear is identity
}

// ---------------- fused 2-ch conv3x3 + relu + conv3x3 -> out
__global__ __launch_bounds__(1024) void k_fuse_conv(const float* __restrict__ c_up,
    const float* __restrict__ f_map, const float* __restrict__ fW1,
    const float* __restrict__ fb1, const float* __restrict__ fW2,
    const float* __restrict__ fb2, float* __restrict__ outp) {
  int b = blockIdx.x;
  int t = threadIdx.x;
  int y = t >> 5, x = t & 31;
  __shared__ float fin[2][1024];
  __shared__ float hb[2][1024];
  fin[0][t] = c_up[b * 1024 + t];
  fin[1][t] = f_map[b * 1024 + t];
  __syncthreads();
  for (int oc = 0; oc < 2; ++oc) {
    float a = fb1[oc];
    #pragma unroll
    for (int ic = 0; ic < 2; ++ic)
      #pragma unroll
      for (int ky = 0; ky < 3; ++ky)
        #pragma unroll
        for (int kx = 0; kx < 3; ++kx) {
          int yy = y + ky - 1, xx = x + kx - 1;
          float v = (yy >= 0 && yy < 32 && xx >= 0 && xx < 32)
                        ? fin[ic][yy * 32 + xx] : 0.f;
          a += v * fW1[((oc * 2 + ic) * 3 + ky) * 3 + kx];
        }
    hb[oc][t] = fmaxf(a, 0.f);
  }
  __syncthreads();
  float a = fb2[0];
  #pragma unroll
  for (int ic = 0; ic < 2; ++ic)
    #pragma unroll
    for (int ky = 0; ky < 3; ++ky)
      #pragma unroll
      for (int kx = 0; kx < 3; ++kx) {
        int yy = y + ky - 1, xx = x + kx - 1;
        float v = (yy >= 0 && yy < 32 && xx >= 0 && xx < 32)
                      ? hb[ic][yy * 32 + xx] : 0.f;
        a += v * fW2[(ic * 3 + ky) * 3 + kx];
      }
  outp[b * 1024 + t] = a;
}

extern "C" void kernel_launch(void* const* d_in, const int* in_sizes, int n_in,
                              void* d_out, int out_size, void* d_ws, size_t ws_size,
                              hipStream_t stream) {
  const float* x    = (const float*)d_in[0];
  const float* Wpc  = (const float*)d_in[1];
  const float* bpc  = (const float*)d_in[2];
  const float* Wpf  = (const float*)d_in[3];
  const float* bpf  = (const float*)d_in[4];
  const float* te   = (const float*)d_in[5];
  const float* ln1g = (const float*)d_in[6];
  const float* ln1b = (const float*)d_in[7];
  const float* Wqkv = (const float*)d_in[8];
  const float* Wo   = (const float*)d_in[9];
  const float* bo   = (const float*)d_in[10];
  const float* ln2g = (const float*)d_in[11];
  const float* ln2b = (const float*)d_in[12];
  const float* W1   = (const float*)d_in[13];
  const float* b1   = (const float*)d_in[14];
  const float* W2   = (const float*)d_in[15];
  const float* b2   = (const float*)d_in[16];
  const float* dWc  = (const float*)d_in[17];
  const float* dbc  = (const float*)d_in[18];
  const float* dWf  = (const float*)d_in[19];
  const float* dbf  = (const float*)d_in[20];
  const float* fW1  = (const float*)d_in[21];
  const float* fb1  = (const float*)d_in[22];
  const float* fW2  = (const float*)d_in[23];
  const float* fb2  = (const float*)d_in[24];

  float* ws = (float*)d_ws;
  float* tokens = ws;                       // 8*1280*128   = 1310720
  float* ybuf   = tokens + 1310720;         // 1310720
  float* qkvb   = ybuf + 1310720;           // 8*1280*384   = 3932160
  float* obuf   = qkvb + 3932160;           // 1310720
  float* hbuf   = obuf + 1310720;           // 8*1280*256   = 2621440
  float* fineb  = hbuf + 2621440;           // 8*1024*128   = 1048576
  float* msort  = fineb + 1048576;          // 8192
  float* c_up   = msort + 8192;             // 8192
  float* f_map  = c_up + 8192;              // 8192
  int*   order  = (int*)(f_map + 8192);     // 8192 ints

  const int M = Bx * NTOK;                  // 10240

  k_coarse<<<Bx * NCc, 128, 0, stream>>>(x, Wpc, bpc, te, tokens);
  k_fine<<<Bx * NFf, 128, 0, stream>>>(x, Wpf, bpf, fineb);
  k_edge_sort<<<Bx, 1024, 0, stream>>>(x, order, msort);
  k_fine_tokens<<<Bx * NFf, 128, 0, stream>>>(fineb, order, msort, te, tokens);

  for (int l = 0; l < LL; ++l) {
    k_ln<<<M, 128, 0, stream>>>(tokens, ln1g + l * DD, ln1b + l * DD, ybuf);
    k_gemm<<<dim3(M / 8, 384 / 32), 256, 8 * 128 * 4, stream>>>(
        ybuf, Wqkv + (size_t)l * DD * 384, nullptr, qkvb, 128, 384, 0, 0);
    k_attn<<<Bx * HEADS * NTOK / 4, 256, 0, stream>>>(qkvb, obuf);
    k_gemm<<<dim3(M / 8, 128 / 32), 256, 8 * 128 * 4, stream>>>(
        obuf, Wo + (size_t)l * DD * DD, bo + l * DD, tokens, 128, 128, 0, 1);
    k_ln<<<M, 128, 0, stream>>>(tokens, ln2g + l * DD, ln2b + l * DD, ybuf);
    k_gemm<<<dim3(M / 8, 256 / 32), 256, 8 * 128 * 4, stream>>>(
        ybuf, W1 + (size_t)l * DD * 256, b1 + l * 256, hbuf, 128, 256, 1, 0);
    k_gemm<<<dim3(M / 8, 128 / 32), 256, 8 * 256 * 4, stream>>>(
        hbuf, W2 + (size_t)l * 256 * DD, b2 + l * DD, tokens, 256, 128, 0, 1);
  }

  k_coarse_dec<<<Bx, 1024, 0, stream>>>(tokens, dWc, dbc, c_up);
  k_fine_dec<<<Bx * NFf / 256, 256, 0, stream>>>(tokens, dWf, dbf, msort, order, f_map);
  k_fuse_conv<<<Bx, 1024, 0, stream>>>(c_up, f_map, fW1, fb1, fW2, fb2, (float*)d_out);
}

// Round 2
// 724.591 us; speedup vs baseline: 3.3715x; 3.3715x over previous
//
#include <hip/hip_runtime.h>
#include <math.h>

#define Bx 8
#define IMG 128
#define DD 128
#define HEADS 4
#define LL 2
#define PCc 8
#define PFf 4
#define HCc 16
#define NCc 256
#define HFf 32
#define NFf 1024
#define NTOK 1280
#define HD 32

typedef __attribute__((ext_vector_type(8))) short short8;
typedef __attribute__((ext_vector_type(4))) float f32x4;

__device__ __forceinline__ short f2bf(float f) {
  unsigned u = __builtin_bit_cast(unsigned, f);
  u += 0x7FFF + ((u >> 16) & 1);   // RNE
  return (short)(u >> 16);
}

// ---------------- coarse patch embed: tokens[:, :256] = patch@Wpc + bpc + te[0]
__global__ __launch_bounds__(128) void k_coarse(const float* __restrict__ x,
    const float* __restrict__ Wpc, const float* __restrict__ bpc,
    const float* __restrict__ te, float* __restrict__ tokens) {
  int blk = blockIdx.x;            // b*NC + t
  int b = blk / NCc, t = blk % NCc;
  int hc = t / HCc, wc = t % HCc;
  int d = threadIdx.x;
  __shared__ float patch[PCc * PCc];
  if (d < PCc * PCc) {
    int pi = d / PCc, pj = d % PCc;
    patch[d] = x[(b * IMG + hc * PCc + pi) * IMG + wc * PCc + pj];
  }
  __syncthreads();
  float acc = bpc[d] + te[d];
  #pragma unroll 8
  for (int i = 0; i < PCc * PCc; ++i) acc += patch[i] * Wpc[i * DD + d];
  tokens[(size_t)(b * NTOK + t) * DD + d] = acc;
}

// ---------------- fine patch embed -> fine buffer [B,NF,D]
__global__ __launch_bounds__(128) void k_fine(const float* __restrict__ x,
    const float* __restrict__ Wpf, const float* __restrict__ bpf,
    float* __restrict__ fineb) {
  int blk = blockIdx.x;            // b*NF + t
  int b = blk / NFf, t = blk % NFf;
  int hf = t / HFf, wf = t % HFf;
  int d = threadIdx.x;
  __shared__ float patch[PFf * PFf];
  if (d < PFf * PFf) {
    int pi = d / PFf, pj = d % PFf;
    patch[d] = x[(b * IMG + hf * PFf + pi) * IMG + wf * PFf + pj];
  }
  __syncthreads();
  float acc = bpf[d];
  #pragma unroll
  for (int i = 0; i < PFf * PFf; ++i) acc += patch[i] * Wpf[i * DD + d];
  fineb[(size_t)(b * NFf + t) * DD + d] = acc;
}

// ---------------- sobel -> avgpool4 -> mask -> stable sort (prefix-sum) per image
__global__ __launch_bounds__(1024) void k_edge_sort(const float* __restrict__ x,
    int* __restrict__ order, float* __restrict__ msort) {
  int b = blockIdx.x;
  int t = threadIdx.x;             // 0..1023 -> fine cell (fy,fx)
  int fy = t >> 5, fx = t & 31;
  const float* img = x + (size_t)b * IMG * IMG;
  float s = 0.f;
  for (int dy = 0; dy < 4; ++dy) {
    for (int dx = 0; dx < 4; ++dx) {
      int py = fy * 4 + dy, px = fx * 4 + dx;
      float v[3][3];
      #pragma unroll
      for (int ky = 0; ky < 3; ++ky)
        #pragma unroll
        for (int kx = 0; kx < 3; ++kx) {
          int yy = py + ky - 1, xx = px + kx - 1;
          v[ky][kx] = (yy >= 0 && yy < IMG && xx >= 0 && xx < IMG)
                          ? img[yy * IMG + xx] : 0.f;
        }
      float gx = -v[0][0] + v[0][2] - 2.f * v[1][0] + 2.f * v[1][2] - v[2][0] + v[2][2];
      float gy = -v[0][0] - 2.f * v[0][1] - v[0][2] + v[2][0] + 2.f * v[2][1] + v[2][2];
      s += sqrtf(gx * gx + gy * gy);
    }
  }
  float e = s * (1.f / 16.f);
  __shared__ float red[1024];
  red[t] = e;
  __syncthreads();
  for (int off = 512; off > 0; off >>= 1) {
    if (t < off) red[t] += red[t + off];
    __syncthreads();
  }
  float mean = red[0] * (1.f / 1024.f);
  int m = (e > mean) ? 1 : 0;
  __shared__ int ps[1024];
  ps[t] = m;
  __syncthreads();
  for (int off = 1; off < 1024; off <<= 1) {
    int v2 = (t >= off) ? ps[t - off] : 0;
    __syncthreads();
    ps[t] += v2;
    __syncthreads();
  }
  int total = ps[1023];
  int incl = ps[t];
  int excl = incl - m;
  int pos = m ? excl : (total + t - excl);
  order[b * NFf + pos] = t;
  msort[b * NFf + pos] = (float)m;
}

// ---------------- gather fine tokens into tokens[:, 256:]
__global__ __launch_bounds__(128) void k_fine_tokens(const float* __restrict__ fineb,
    const int* __restrict__ order, const float* __restrict__ msort,
    const float* __restrict__ te, float* __restrict__ tokens) {
  int blk = blockIdx.x;            // b*NF + j
  int b = blk / NFf, j = blk % NFf;
  int d = threadIdx.x;
  int src = order[b * NFf + j];
  float v = fineb[(size_t)(b * NFf + src) * DD + d] * msort[b * NFf + j] + te[DD + d];
  tokens[(size_t)(b * NTOK + NCc + j) * DD + d] = v;
}

// ---------------- LayerNorm over D=128, one block per row
__global__ __launch_bounds__(128) void k_ln(const float* __restrict__ inp,
    const float* __restrict__ g, const float* __restrict__ bb,
    float* __restrict__ outp) {
  int row = blockIdx.x;
  int d = threadIdx.x;
  float v = inp[(size_t)row * DD + d];
  __shared__ float red[DD];
  red[d] = v;
  __syncthreads();
  for (int off = 64; off > 0; off >>= 1) {
    if (d < off) red[d] += red[d + off];
    __syncthreads();
  }
  float mean = red[0] * (1.f / DD);
  __syncthreads();
  float c = v - mean;
  red[d] = c * c;
  __syncthreads();
  for (int off = 64; off > 0; off >>= 1) {
    if (d < off) red[d] += red[d + off];
    __syncthreads();
  }
  float var = red[0] * (1.f / DD);
  outp[(size_t)row * DD + d] = c * rsqrtf(var + 1e-5f) * g[d] + bb[d];
}

// ---------------- generic GEMM: C[M,Nout] = act(A[M,K]@W + bias) (+=C if resid)
// block = 256 threads = 8 rows x 32 cols; dyn-LDS = 8*K floats
__global__ __launch_bounds__(256) void k_gemm(const float* __restrict__ A,
    const float* __restrict__ W, const float* __restrict__ bias,
    float* __restrict__ C, int K, int Nout, int do_gelu, int do_resid) {
  extern __shared__ float Atile[];   // 8*K
  int row0 = blockIdx.x * 8;
  int col0 = blockIdx.y * 32;
  for (int idx = threadIdx.x; idx < 8 * K; idx += 256)
    Atile[idx] = A[(size_t)(row0 + idx / K) * K + (idx % K)];
  __syncthreads();
  int tx = threadIdx.x & 31, ty = threadIdx.x >> 5;
  int col = col0 + tx;
  const float* Arow = Atile + ty * K;
  float acc = 0.f;
  for (int k = 0; k < K; ++k) acc += Arow[k] * W[(size_t)k * Nout + col];
  if (bias) acc += bias[col];
  if (do_gelu) acc = 0.5f * acc * (1.f + erff(acc * 0.70710678118654752f));
  float* op = &C[(size_t)(row0 + ty) * Nout + col];
  if (do_resid) *op += acc; else *op = acc;
}

// ---------------- flash attention, bf16 MFMA 16x16x32
// grid = B*H*(NTOK/64); block = 256 (4 waves x 16 queries)
// qkv layout [B*N, 384]: q at h*32, k at 128+h*32, v at 256+h*32
__global__ __launch_bounds__(256) void k_attn_mfma(const float* __restrict__ qkv,
    float* __restrict__ obuf) {
  __shared__ short Ks[64 * 32];      // [key][d], row = 32 bf16 = 64 B
  __shared__ short Vt[32 * 72];      // [d][key], padded stride 72
  __shared__ short Pl[4][16 * 72];   // per-wave P [q][key], stride 72

  int qt = blockIdx.x % (NTOK / 64);
  int h  = (blockIdx.x / (NTOK / 64)) % HEADS;
  int b  = blockIdx.x / (NTOK / 64 * HEADS);
  int lane = threadIdx.x & 63, w = threadIdx.x >> 6;
  int m = lane & 15, quad = lane >> 4;
  int q0 = qt * 64 + w * 16;

  const float scale = 0.17677669529663687f;  // 1/sqrt(32)
  // Q fragment (A-layout): row m, dims quad*8..+8, pre-scaled
  const float* qr = qkv + ((size_t)(b * NTOK) + q0 + m) * 384 + h * HD + quad * 8;
  float4 qa = ((const float4*)qr)[0];
  float4 qb = ((const float4*)qr)[1];
  short8 qf;
  qf[0] = f2bf(qa.x * scale); qf[1] = f2bf(qa.y * scale);
  qf[2] = f2bf(qa.z * scale); qf[3] = f2bf(qa.w * scale);
  qf[4] = f2bf(qb.x * scale); qf[5] = f2bf(qb.y * scale);
  qf[6] = f2bf(qb.z * scale); qf[7] = f2bf(qb.w * scale);

  f32x4 zero = {0.f, 0.f, 0.f, 0.f};
  f32x4 Oacc[2] = {zero, zero};
  float mrow[4] = {-1e30f, -1e30f, -1e30f, -1e30f};
  float lrow[4] = {0.f, 0.f, 0.f, 0.f};

  int t = threadIdx.x;
  int skey = t >> 2, sdseg = t & 3;  // staging: key 0..63, 8 dims each
  const float* kstage = qkv + ((size_t)(b * NTOK) + skey) * 384 + 128 + h * HD + sdseg * 8;
  const float* vstage = kstage + 128;

  for (int s = 0; s < 20; ++s) {
    __syncthreads();   // previous stage's Ks/Vt reads complete
    {
      const float* kr = kstage + (size_t)s * 64 * 384;
      float4 k1 = ((const float4*)kr)[0];
      float4 k2 = ((const float4*)kr)[1];
      short8 kf;
      kf[0] = f2bf(k1.x); kf[1] = f2bf(k1.y); kf[2] = f2bf(k1.z); kf[3] = f2bf(k1.w);
      kf[4] = f2bf(k2.x); kf[5] = f2bf(k2.y); kf[6] = f2bf(k2.z); kf[7] = f2bf(k2.w);
      *(short8*)&Ks[skey * 32 + sdseg * 8] = kf;
      const float* vr = vstage + (size_t)s * 64 * 384;
      float4 v1 = ((const float4*)vr)[0];
      float4 v2 = ((const float4*)vr)[1];
      Vt[(sdseg * 8 + 0) * 72 + skey] = f2bf(v1.x);
      Vt[(sdseg * 8 + 1) * 72 + skey] = f2bf(v1.y);
      Vt[(sdseg * 8 + 2) * 72 + skey] = f2bf(v1.z);
      Vt[(sdseg * 8 + 3) * 72 + skey] = f2bf(v1.w);
      Vt[(sdseg * 8 + 4) * 72 + skey] = f2bf(v2.x);
      Vt[(sdseg * 8 + 5) * 72 + skey] = f2bf(v2.y);
      Vt[(sdseg * 8 + 6) * 72 + skey] = f2bf(v2.z);
      Vt[(sdseg * 8 + 7) * 72 + skey] = f2bf(v2.w);
    }
    __syncthreads();

    // ---- S = Q K^T for 4 col-tiles of 16 keys (C-layout: row=4*quad+reg, col=lane&15)
    f32x4 sc[4];
    #pragma unroll
    for (int ct = 0; ct < 4; ++ct) {
      short8 kfrag = *(const short8*)&Ks[(ct * 16 + m) * 32 + quad * 8];
      sc[ct] = __builtin_amdgcn_mfma_f32_16x16x32_bf16(qf, kfrag, zero, 0, 0, 0);
    }
    // ---- online softmax (rows owned by 16-lane groups sharing `quad`)
    float mloc[4], psum[4];
    #pragma unroll
    for (int r = 0; r < 4; ++r) {
      float mx = fmaxf(fmaxf(sc[0][r], sc[1][r]), fmaxf(sc[2][r], sc[3][r]));
      #pragma unroll
      for (int o = 1; o < 16; o <<= 1) mx = fmaxf(mx, __shfl_xor(mx, o));
      float mnew = fmaxf(mrow[r], mx);
      float alpha = __expf(mrow[r] - mnew);
      mrow[r] = mnew;
      mloc[r] = alpha;
      float ssum = 0.f;
      #pragma unroll
      for (int ct = 0; ct < 4; ++ct) {
        float p = __expf(sc[ct][r] - mnew);
        sc[ct][r] = p;
        ssum += p;
      }
      psum[r] = ssum;
    }
    #pragma unroll
    for (int r = 0; r < 4; ++r) {
      float ssum = psum[r];
      #pragma unroll
      for (int o = 1; o < 16; o <<= 1) ssum += __shfl_xor(ssum, o);
      lrow[r] = lrow[r] * mloc[r] + ssum;
      Oacc[0][r] *= mloc[r];
      Oacc[1][r] *= mloc[r];
    }
    // ---- P (bf16) to per-wave LDS, C-layout -> A-layout round trip
    #pragma unroll
    for (int ct = 0; ct < 4; ++ct)
      #pragma unroll
      for (int r = 0; r < 4; ++r)
        Pl[w][(quad * 4 + r) * 72 + ct * 16 + m] = f2bf(sc[ct][r]);
    // ---- O += P @ V   (A = P [16q x 64k], B = V via Vt [d][key])
    #pragma unroll
    for (int ks = 0; ks < 2; ++ks) {
      short8 pfrag = *(const short8*)&Pl[w][m * 72 + ks * 32 + quad * 8];
      #pragma unroll
      for (int nt = 0; nt < 2; ++nt) {
        short8 vfrag = *(const short8*)&Vt[(nt * 16 + m) * 72 + ks * 32 + quad * 8];
        Oacc[nt] = __builtin_amdgcn_mfma_f32_16x16x32_bf16(pfrag, vfrag, Oacc[nt], 0, 0, 0);
      }
    }
  }
  // ---- write O / l  (C-layout: row q = 4*quad+reg, col d = nt*16 + m)
  #pragma unroll
  for (int r = 0; r < 4; ++r) {
    float rs = 1.f / lrow[r];
    int q = q0 + quad * 4 + r;
    #pragma unroll
    for (int nt = 0; nt < 2; ++nt)
      obuf[(size_t)(b * NTOK + q) * DD + h * HD + nt * 16 + m] = Oacc[nt][r] * rs;
  }
}

// ---------------- coarse decoder head + 16->32 align-corners bilinear
__global__ __launch_bounds__(1024) void k_coarse_dec(const float* __restrict__ tokens,
    const float* __restrict__ dWc, const float* __restrict__ dbc,
    float* __restrict__ c_up) {
  int b = blockIdx.x;
  int t = threadIdx.x;
  __shared__ float c[NCc];
  if (t < NCc) {
    const float* row = tokens + (size_t)(b * NTOK + t) * DD;
    float a = 0.f;
    for (int d = 0; d < DD; ++d) a += row[d] * dWc[d];
    c[t] = a + dbc[0];
  }
  __syncthreads();
  int oy = t >> 5, ox = t & 31;
  float ys = oy * (15.f / 31.f);
  float xs = ox * (15.f / 31.f);
  int y0 = (int)floorf(ys); int y1 = min(y0 + 1, 15); float wy = ys - (float)y0;
  int x0 = (int)floorf(xs); int x1 = min(x0 + 1, 15); float wx = xs - (float)x0;
  float v = c[y0 * 16 + x0] * (1.f - wy) * (1.f - wx)
          + c[y0 * 16 + x1] * (1.f - wy) * wx
          + c[y1 * 16 + x0] * wy * (1.f - wx)
          + c[y1 * 16 + x1] * wy * wx;
  c_up[b * 1024 + t] = v;
}

// ---------------- fine decoder head, mask, scatter back to pixel order
__global__ __launch_bounds__(256) void k_fine_dec(const float* __restrict__ tokens,
    const float* __restrict__ dWf, const float* __restrict__ dbf,
    const float* __restrict__ msort, const int* __restrict__ order,
    float* __restrict__ f_map) {
  int idx = blockIdx.x * 256 + threadIdx.x;  // b*NF + j
  int b = idx >> 10, j = idx & 1023;
  const float* row = tokens + (size_t)(b * NTOK + NCc + j) * DD;
  float a = 0.f;
  for (int d = 0; d < DD; ++d) a += row[d] * dWf[d];
  a = (a + dbf[0]) * msort[b * NFf + j];
  f_map[b * NFf + order[b * NFf + j]] = a;  // 32->32 AC-bilinear is identity
}

// ---------------- fused 2-ch conv3x3 + relu + conv3x3 -> out
__global__ __launch_bounds__(1024) void k_fuse_conv(const float* __restrict__ c_up,
    const float* __restrict__ f_map, const float* __restrict__ fW1,
    const float* __restrict__ fb1, const float* __restrict__ fW2,
    const float* __restrict__ fb2, float* __restrict__ outp) {
  int b = blockIdx.x;
  int t = threadIdx.x;
  int y = t >> 5, x = t & 31;
  __shared__ float fin[2][1024];
  __shared__ float hb[2][1024];
  fin[0][t] = c_up[b * 1024 + t];
  fin[1][t] = f_map[b * 1024 + t];
  __syncthreads();
  for (int oc = 0; oc < 2; ++oc) {
    float a = fb1[oc];
    #pragma unroll
    for (int ic = 0; ic < 2; ++ic)
      #pragma unroll
      for (int ky = 0; ky < 3; ++ky)
        #pragma unroll
        for (int kx = 0; kx < 3; ++kx) {
          int yy = y + ky - 1, xx = x + kx - 1;
          float v = (yy >= 0 && yy < 32 && xx >= 0 && xx < 32)
                        ? fin[ic][yy * 32 + xx] : 0.f;
          a += v * fW1[((oc * 2 + ic) * 3 + ky) * 3 + kx];
        }
    hb[oc][t] = fmaxf(a, 0.f);
  }
  __syncthreads();
  float a = fb2[0];
  #pragma unroll
  for (int ic = 0; ic < 2; ++ic)
    #pragma unroll
    for (int ky = 0; ky < 3; ++ky)
      #pragma unroll
      for (int kx = 0; kx < 3; ++kx) {
        int yy = y + ky - 1, xx = x + kx - 1;
        float v = (yy >= 0 && yy < 32 && xx >= 0 && xx < 32)
                      ? hb[ic][yy * 32 + xx] : 0.f;
        a += v * fW2[(ic * 3 + ky) * 3 + kx];
      }
  outp[b * 1024 + t] = a;
}

extern "C" void kernel_launch(void* const* d_in, const int* in_sizes, int n_in,
                              void* d_out, int out_size, void* d_ws, size_t ws_size,
                              hipStream_t stream) {
  const float* x    = (const float*)d_in[0];
  const float* Wpc  = (const float*)d_in[1];
  const float* bpc  = (const float*)d_in[2];
  const float* Wpf  = (const float*)d_in[3];
  const float* bpf  = (const float*)d_in[4];
  const float* te   = (const float*)d_in[5];
  const float* ln1g = (const float*)d_in[6];
  const float* ln1b = (const float*)d_in[7];
  const float* Wqkv = (const float*)d_in[8];
  const float* Wo   = (const float*)d_in[9];
  const float* bo   = (const float*)d_in[10];
  const float* ln2g = (const float*)d_in[11];
  const float* ln2b = (const float*)d_in[12];
  const float* W1   = (const float*)d_in[13];
  const float* b1   = (const float*)d_in[14];
  const float* W2   = (const float*)d_in[15];
  const float* b2   = (const float*)d_in[16];
  const float* dWc  = (const float*)d_in[17];
  const float* dbc  = (const float*)d_in[18];
  const float* dWf  = (const float*)d_in[19];
  const float* dbf  = (const float*)d_in[20];
  const float* fW1  = (const float*)d_in[21];
  const float* fb1  = (const float*)d_in[22];
  const float* fW2  = (const float*)d_in[23];
  const float* fb2  = (const float*)d_in[24];

  float* ws = (float*)d_ws;
  float* tokens = ws;                       // 8*1280*128   = 1310720
  float* ybuf   = tokens + 1310720;         // 1310720
  float* qkvb   = ybuf + 1310720;           // 8*1280*384   = 3932160
  float* obuf   = qkvb + 3932160;           // 1310720
  float* hbuf   = obuf + 1310720;           // 8*1280*256   = 2621440
  float* fineb  = hbuf + 2621440;           // 8*1024*128   = 1048576
  float* msort  = fineb + 1048576;          // 8192
  float* c_up   = msort + 8192;             // 8192
  float* f_map  = c_up + 8192;              // 8192
  int*   order  = (int*)(f_map + 8192);     // 8192 ints

  const int M = Bx * NTOK;                  // 10240

  k_coarse<<<Bx * NCc, 128, 0, stream>>>(x, Wpc, bpc, te, tokens);
  k_fine<<<Bx * NFf, 128, 0, stream>>>(x, Wpf, bpf, fineb);
  k_edge_sort<<<Bx, 1024, 0, stream>>>(x, order, msort);
  k_fine_tokens<<<Bx * NFf, 128, 0, stream>>>(fineb, order, msort, te, tokens);

  for (int l = 0; l < LL; ++l) {
    k_ln<<<M, 128, 0, stream>>>(tokens, ln1g + l * DD, ln1b + l * DD, ybuf);
    k_gemm<<<dim3(M / 8, 384 / 32), 256, 8 * 128 * 4, stream>>>(
        ybuf, Wqkv + (size_t)l * DD * 384, nullptr, qkvb, 128, 384, 0, 0);
    k_attn_mfma<<<Bx * HEADS * (NTOK / 64), 256, 0, stream>>>(qkvb, obuf);
    k_gemm<<<dim3(M / 8, 128 / 32), 256, 8 * 128 * 4, stream>>>(
        obuf, Wo + (size_t)l * DD * DD, bo + l * DD, tokens, 128, 128, 0, 1);
    k_ln<<<M, 128, 0, stream>>>(tokens, ln2g + l * DD, ln2b + l * DD, ybuf);
    k_gemm<<<dim3(M / 8, 256 / 32), 256, 8 * 128 * 4, stream>>>(
        ybuf, W1 + (size_t)l * DD * 256, b1 + l * 256, hbuf, 128, 256, 1, 0);
    k_gemm<<<dim3(M / 8, 128 / 32), 256, 8 * 256 * 4, stream>>>(
        hbuf, W2 + (size_t)l * 256 * DD, b2 + l * DD, tokens, 256, 128, 0, 1);
  }

  k_coarse_dec<<<Bx, 1024, 0, stream>>>(tokens, dWc, dbc, c_up);
  k_fine_dec<<<Bx * NFf / 256, 256, 0, stream>>>(tokens, dWf, dbf, msort, order, f_map);
  k_fuse_conv<<<Bx, 1024, 0, stream>>>(c_up, f_map, fW1, fb1, fW2, fb2, (float*)d_out);
}

// Round 3
// 339.064 us; speedup vs baseline: 7.2050x; 2.1370x over previous
//
#include <hip/hip_runtime.h>
#include <math.h>

#define Bx 8
#define IMG 128
#define DD 128
#define HEADS 4
#define LL 2
#define PCc 8
#define PFf 4
#define HCc 16
#define NCc 256
#define HFf 32
#define NFf 1024
#define NTOK 1280
#define HD 32

typedef __attribute__((ext_vector_type(8))) short short8;
typedef __attribute__((ext_vector_type(4))) float f32x4;

__device__ __forceinline__ short f2bf(float f) {
  unsigned u = __builtin_bit_cast(unsigned, f);
  u += 0x7FFF + ((u >> 16) & 1);   // RNE
  return (short)(u >> 16);
}

// ---------------- coarse patch embed: tokens[:, :256] = patch@Wpc + bpc + te[0]
__global__ __launch_bounds__(128) void k_coarse(const float* __restrict__ x,
    const float* __restrict__ Wpc, const float* __restrict__ bpc,
    const float* __restrict__ te, float* __restrict__ tokens) {
  int blk = blockIdx.x;            // b*NC + t
  int b = blk / NCc, t = blk % NCc;
  int hc = t / HCc, wc = t % HCc;
  int d = threadIdx.x;
  __shared__ float patch[PCc * PCc];
  if (d < PCc * PCc) {
    int pi = d / PCc, pj = d % PCc;
    patch[d] = x[(b * IMG + hc * PCc + pi) * IMG + wc * PCc + pj];
  }
  __syncthreads();
  float acc = bpc[d] + te[d];
  #pragma unroll 8
  for (int i = 0; i < PCc * PCc; ++i) acc += patch[i] * Wpc[i * DD + d];
  tokens[(size_t)(b * NTOK + t) * DD + d] = acc;
}

// ---------------- fine patch embed -> fine buffer [B,NF,D]
__global__ __launch_bounds__(128) void k_fine(const float* __restrict__ x,
    const float* __restrict__ Wpf, const float* __restrict__ bpf,
    float* __restrict__ fineb) {
  int blk = blockIdx.x;            // b*NF + t
  int b = blk / NFf, t = blk % NFf;
  int hf = t / HFf, wf = t % HFf;
  int d = threadIdx.x;
  __shared__ float patch[PFf * PFf];
  if (d < PFf * PFf) {
    int pi = d / PFf, pj = d % PFf;
    patch[d] = x[(b * IMG + hf * PFf + pi) * IMG + wf * PFf + pj];
  }
  __syncthreads();
  float acc = bpf[d];
  #pragma unroll
  for (int i = 0; i < PFf * PFf; ++i) acc += patch[i] * Wpf[i * DD + d];
  fineb[(size_t)(b * NFf + t) * DD + d] = acc;
}

// ---------------- sobel -> avgpool4 -> mask -> stable sort (prefix-sum) per image
__global__ __launch_bounds__(1024) void k_edge_sort(const float* __restrict__ x,
    int* __restrict__ order, float* __restrict__ msort) {
  int b = blockIdx.x;
  int t = threadIdx.x;             // 0..1023 -> fine cell (fy,fx)
  int fy = t >> 5, fx = t & 31;
  const float* img = x + (size_t)b * IMG * IMG;
  float s = 0.f;
  for (int dy = 0; dy < 4; ++dy) {
    for (int dx = 0; dx < 4; ++dx) {
      int py = fy * 4 + dy, px = fx * 4 + dx;
      float v[3][3];
      #pragma unroll
      for (int ky = 0; ky < 3; ++ky)
        #pragma unroll
        for (int kx = 0; kx < 3; ++kx) {
          int yy = py + ky - 1, xx = px + kx - 1;
          v[ky][kx] = (yy >= 0 && yy < IMG && xx >= 0 && xx < IMG)
                          ? img[yy * IMG + xx] : 0.f;
        }
      float gx = -v[0][0] + v[0][2] - 2.f * v[1][0] + 2.f * v[1][2] - v[2][0] + v[2][2];
      float gy = -v[0][0] - 2.f * v[0][1] - v[0][2] + v[2][0] + 2.f * v[2][1] + v[2][2];
      s += sqrtf(gx * gx + gy * gy);
    }
  }
  float e = s * (1.f / 16.f);
  __shared__ float red[1024];
  red[t] = e;
  __syncthreads();
  for (int off = 512; off > 0; off >>= 1) {
    if (t < off) red[t] += red[t + off];
    __syncthreads();
  }
  float mean = red[0] * (1.f / 1024.f);
  int m = (e > mean) ? 1 : 0;
  __shared__ int ps[1024];
  ps[t] = m;
  __syncthreads();
  for (int off = 1; off < 1024; off <<= 1) {
    int v2 = (t >= off) ? ps[t - off] : 0;
    __syncthreads();
    ps[t] += v2;
    __syncthreads();
  }
  int total = ps[1023];
  int incl = ps[t];
  int excl = incl - m;
  int pos = m ? excl : (total + t - excl);
  order[b * NFf + pos] = t;
  msort[b * NFf + pos] = (float)m;
}

// ---------------- gather fine tokens into tokens[:, 256:]
__global__ __launch_bounds__(128) void k_fine_tokens(const float* __restrict__ fineb,
    const int* __restrict__ order, const float* __restrict__ msort,
    const float* __restrict__ te, float* __restrict__ tokens) {
  int blk = blockIdx.x;            // b*NF + j
  int b = blk / NFf, j = blk % NFf;
  int d = threadIdx.x;
  int src = order[b * NFf + j];
  float v = fineb[(size_t)(b * NFf + src) * DD + d] * msort[b * NFf + j] + te[DD + d];
  tokens[(size_t)(b * NTOK + NCc + j) * DD + d] = v;
}

// ---------------- weight prep: transpose + bf16 for all encoder GEMM weights
// WtQKV [L][384][128], WtO [L][128][128], Wt1 [L][256][128], Wt2 [L][128][256]
__global__ __launch_bounds__(256) void k_prep_w(const float* __restrict__ Wqkv,
    const float* __restrict__ Wo, const float* __restrict__ W1,
    const float* __restrict__ W2, short* __restrict__ WtQKV,
    short* __restrict__ WtO, short* __restrict__ Wt1, short* __restrict__ Wt2) {
  int idx = blockIdx.x * 256 + threadIdx.x;   // 0 .. 262143
  int l = idx / 131072, r = idx % 131072;
  const float* src; short* dst; int N, off;
  if (r < 49152)      { src = Wqkv + l * 49152; dst = WtQKV + l * 49152; N = 384; off = r; }
  else if (r < 65536) { src = Wo + l * 16384;  dst = WtO + l * 16384;  N = 128; off = r - 49152; }
  else if (r < 98304) { src = W1 + l * 32768;  dst = Wt1 + l * 32768;  N = 256; off = r - 65536; }
  else                { src = W2 + l * 32768;  dst = Wt2 + l * 32768;  N = 128; off = r - 98304; }
  int k = off / N, n = off % N;
  int K = 131072 / N / 8;   // qkv:128/... careful: derive K from pair
  // K is 128 except W2 (256); recompute directly:
  K = (r >= 98304) ? 256 : 128;
  dst[(size_t)n * K + k] = f2bf(src[off]);
}

// ---------------- LayerNorm over D=128, one wave per row, out bf16
__global__ __launch_bounds__(256) void k_ln_bf16(const float* __restrict__ inp,
    const float* __restrict__ g, const float* __restrict__ bb,
    short* __restrict__ outp) {
  int row = blockIdx.x * 4 + (threadIdx.x >> 6);
  int lane = threadIdx.x & 63;
  float2 v = ((const float2*)(inp + (size_t)row * DD))[lane];
  float s = v.x + v.y;
  #pragma unroll
  for (int o = 32; o > 0; o >>= 1) s += __shfl_xor(s, o, 64);
  float mean = s * (1.f / 128.f);
  float cx = v.x - mean, cy = v.y - mean;
  float q = cx * cx + cy * cy;
  #pragma unroll
  for (int o = 32; o > 0; o >>= 1) q += __shfl_xor(q, o, 64);
  float rstd = rsqrtf(q * (1.f / 128.f) + 1e-5f);
  float2 gg = ((const float2*)g)[lane];
  float2 bv = ((const float2*)bb)[lane];
  int p = (int)(unsigned short)f2bf(cx * rstd * gg.x + bv.x)
        | ((int)(unsigned short)f2bf(cy * rstd * gg.y + bv.y) << 16);
  ((int*)(outp + (size_t)row * DD))[lane] = p;
}

// ---------------- MFMA GEMM: C[M,N] = act(A_bf16[M,K] @ W + bias)
// Wt is bf16 [N][K] (pre-transposed). If Cf: fp32 residual +=. Else Cb: bf16 out.
// block 256 = 4 waves; tile 64 rows x 64 cols; K chunked at 128.
__global__ __launch_bounds__(256) void k_gemm_mfma(const short* __restrict__ A,
    const short* __restrict__ Wt, const float* __restrict__ bias,
    float* __restrict__ Cf, short* __restrict__ Cb, int K, int N, int do_gelu) {
  __shared__ short Alds[64 * 136];   // stride 136: +4 dword bank advance per row
  __shared__ short Blds[64 * 136];
  int row0 = blockIdx.x * 64, col0 = blockIdx.y * 64;
  int t = threadIdx.x;
  int lane = t & 63, w = t >> 6;
  int m = lane & 15, quad = lane >> 4;
  f32x4 zero = {0.f, 0.f, 0.f, 0.f};
  f32x4 acc[4] = {zero, zero, zero, zero};

  for (int kb = 0; kb < K; kb += 128) {
    __syncthreads();
    #pragma unroll
    for (int j = 0; j < 4; ++j) {
      int i = t + j * 256;          // 1024 short8 per tile
      int r = i >> 4, kk = (i & 15) * 8;
      *(short8*)&Alds[r * 136 + kk] =
          *(const short8*)&A[(size_t)(row0 + r) * K + kb + kk];
      *(short8*)&Blds[r * 136 + kk] =
          *(const short8*)&Wt[(size_t)(col0 + r) * K + kb + kk];
    }
    __syncthreads();
    const short* Abase = Alds + (w * 16 + m) * 136 + quad * 8;
    const short* Bbase = Blds + m * 136 + quad * 8;
    #pragma unroll
    for (int ks = 0; ks < 128; ks += 32) {
      short8 af = *(const short8*)(Abase + ks);
      #pragma unroll
      for (int nt = 0; nt < 4; ++nt) {
        short8 bf = *(const short8*)(Bbase + nt * 16 * 136 + ks);
        acc[nt] = __builtin_amdgcn_mfma_f32_16x16x32_bf16(af, bf, acc[nt], 0, 0, 0);
      }
    }
  }
  // epilogue: C-layout row = quad*4+r, col = nt*16+m
  #pragma unroll
  for (int nt = 0; nt < 4; ++nt) {
    int col = col0 + nt * 16 + m;
    float bv = bias ? bias[col] : 0.f;
    #pragma unroll
    for (int r = 0; r < 4; ++r) {
      int row = row0 + w * 16 + quad * 4 + r;
      float v = acc[nt][r] + bv;
      if (do_gelu) v = 0.5f * v * (1.f + erff(v * 0.70710678118654752f));
      if (Cf) Cf[(size_t)row * N + col] += v;
      else    Cb[(size_t)row * N + col] = f2bf(v);
    }
  }
}

// ---------------- flash attention, bf16 MFMA 16x16x32, bf16 qkv in / bf16 o out
// grid = B*H*(NTOK/64); block = 256 (4 waves x 16 queries)
// qkv layout [B*N, 384] bf16: q at h*32, k at 128+h*32, v at 256+h*32
__global__ __launch_bounds__(256) void k_attn_mfma(const short* __restrict__ qkv,
    short* __restrict__ obuf) {
  __shared__ short Ks[64 * 32];      // [key][d]
  __shared__ short Vt[32 * 72];      // [d][key], padded stride 72
  __shared__ short Pl[4][16 * 72];   // per-wave P [q][key], stride 72

  int qt = blockIdx.x % (NTOK / 64);
  int h  = (blockIdx.x / (NTOK / 64)) % HEADS;
  int b  = blockIdx.x / (NTOK / 64 * HEADS);
  int lane = threadIdx.x & 63, w = threadIdx.x >> 6;
  int m = lane & 15, quad = lane >> 4;
  int q0 = qt * 64 + w * 16;

  const float scale = 0.17677669529663687f;  // 1/sqrt(32)
  const short* qr = qkv + ((size_t)(b * NTOK) + q0 + m) * 384 + h * HD + quad * 8;
  short8 qf = *(const short8*)qr;

  f32x4 zero = {0.f, 0.f, 0.f, 0.f};
  f32x4 Oacc[2] = {zero, zero};
  float mrow[4] = {-1e30f, -1e30f, -1e30f, -1e30f};
  float lrow[4] = {0.f, 0.f, 0.f, 0.f};

  int t = threadIdx.x;
  int skey = t >> 2, sdseg = t & 3;  // staging: key 0..63, 8 dims each
  const short* kstage = qkv + ((size_t)(b * NTOK) + skey) * 384 + 128 + h * HD + sdseg * 8;

  for (int s = 0; s < 20; ++s) {
    __syncthreads();   // previous stage's Ks/Vt reads complete
    {
      short8 kf = *(const short8*)(kstage + (size_t)s * 64 * 384);
      *(short8*)&Ks[skey * 32 + sdseg * 8] = kf;
      short8 vf = *(const short8*)(kstage + 128 + (size_t)s * 64 * 384);
      #pragma unroll
      for (int j = 0; j < 8; ++j) Vt[(sdseg * 8 + j) * 72 + skey] = vf[j];
    }
    __syncthreads();

    // ---- S = Q K^T (C-layout: row=4*quad+reg, col=lane&15), then scale
    f32x4 sc[4];
    #pragma unroll
    for (int ct = 0; ct < 4; ++ct) {
      short8 kfrag = *(const short8*)&Ks[(ct * 16 + m) * 32 + quad * 8];
      sc[ct] = __builtin_amdgcn_mfma_f32_16x16x32_bf16(qf, kfrag, zero, 0, 0, 0);
      sc[ct] *= scale;
    }
    // ---- online softmax (rows owned by 16-lane groups sharing `quad`)
    float mloc[4], psum[4];
    #pragma unroll
    for (int r = 0; r < 4; ++r) {
      float mx = fmaxf(fmaxf(sc[0][r], sc[1][r]), fmaxf(sc[2][r], sc[3][r]));
      #pragma unroll
      for (int o = 1; o < 16; o <<= 1) mx = fmaxf(mx, __shfl_xor(mx, o));
      float mnew = fmaxf(mrow[r], mx);
      float alpha = __expf(mrow[r] - mnew);
      mrow[r] = mnew;
      mloc[r] = alpha;
      float ssum = 0.f;
      #pragma unroll
      for (int ct = 0; ct < 4; ++ct) {
        float p = __expf(sc[ct][r] - mnew);
        sc[ct][r] = p;
        ssum += p;
      }
      psum[r] = ssum;
    }
    #pragma unroll
    for (int r = 0; r < 4; ++r) {
      float ssum = psum[r];
      #pragma unroll
      for (int o = 1; o < 16; o <<= 1) ssum += __shfl_xor(ssum, o);
      lrow[r] = lrow[r] * mloc[r] + ssum;
      Oacc[0][r] *= mloc[r];
      Oacc[1][r] *= mloc[r];
    }
    // ---- P (bf16) to per-wave LDS, C-layout -> A-layout round trip
    #pragma unroll
    for (int ct = 0; ct < 4; ++ct)
      #pragma unroll
      for (int r = 0; r < 4; ++r)
        Pl[w][(quad * 4 + r) * 72 + ct * 16 + m] = f2bf(sc[ct][r]);
    // ---- O += P @ V
    #pragma unroll
    for (int ks = 0; ks < 2; ++ks) {
      short8 pfrag = *(const short8*)&Pl[w][m * 72 + ks * 32 + quad * 8];
      #pragma unroll
      for (int nt = 0; nt < 2; ++nt) {
        short8 vfrag = *(const short8*)&Vt[(nt * 16 + m) * 72 + ks * 32 + quad * 8];
        Oacc[nt] = __builtin_amdgcn_mfma_f32_16x16x32_bf16(pfrag, vfrag, Oacc[nt], 0, 0, 0);
      }
    }
  }
  // ---- write O (C-layout: row q = 4*quad+reg, col d = nt*16 + m)
  #pragma unroll
  for (int r = 0; r < 4; ++r) {
    float rs = 1.f / lrow[r];
    int q = q0 + quad * 4 + r;
    #pragma unroll
    for (int nt = 0; nt < 2; ++nt)
      obuf[(size_t)(b * NTOK + q) * DD + h * HD + nt * 16 + m] = f2bf(Oacc[nt][r] * rs);
  }
}

// ---------------- coarse decoder head + 16->32 align-corners bilinear
__global__ __launch_bounds__(1024) void k_coarse_dec(const float* __restrict__ tokens,
    const float* __restrict__ dWc, const float* __restrict__ dbc,
    float* __restrict__ c_up) {
  int b = blockIdx.x;
  int t = threadIdx.x;
  __shared__ float c[NCc];
  if (t < NCc) {
    const float* row = tokens + (size_t)(b * NTOK + t) * DD;
    float a = 0.f;
    for (int d = 0; d < DD; ++d) a += row[d] * dWc[d];
    c[t] = a + dbc[0];
  }
  __syncthreads();
  int oy = t >> 5, ox = t & 31;
  float ys = oy * (15.f / 31.f);
  float xs = ox * (15.f / 31.f);
  int y0 = (int)floorf(ys); int y1 = min(y0 + 1, 15); float wy = ys - (float)y0;
  int x0 = (int)floorf(xs); int x1 = min(x0 + 1, 15); float wx = xs - (float)x0;
  float v = c[y0 * 16 + x0] * (1.f - wy) * (1.f - wx)
          + c[y0 * 16 + x1] * (1.f - wy) * wx
          + c[y1 * 16 + x0] * wy * (1.f - wx)
          + c[y1 * 16 + x1] * wy * wx;
  c_up[b * 1024 + t] = v;
}

// ---------------- fine decoder head, mask, scatter back to pixel order
__global__ __launch_bounds__(256) void k_fine_dec(const float* __restrict__ tokens,
    const float* __restrict__ dWf, const float* __restrict__ dbf,
    const float* __restrict__ msort, const int* __restrict__ order,
    float* __restrict__ f_map) {
  int idx = blockIdx.x * 256 + threadIdx.x;  // b*NF + j
  int b = idx >> 10, j = idx & 1023;
  const float* row = tokens + (size_t)(b * NTOK + NCc + j) * DD;
  float a = 0.f;
  for (int d = 0; d < DD; ++d) a += row[d] * dWf[d];
  a = (a + dbf[0]) * msort[b * NFf + j];
  f_map[b * NFf + order[b * NFf + j]] = a;  // 32->32 AC-bilinear is identity
}

// ---------------- fused 2-ch conv3x3 + relu + conv3x3 -> out
__global__ __launch_bounds__(1024) void k_fuse_conv(const float* __restrict__ c_up,
    const float* __restrict__ f_map, const float* __restrict__ fW1,
    const float* __restrict__ fb1, const float* __restrict__ fW2,
    const float* __restrict__ fb2, float* __restrict__ outp) {
  int b = blockIdx.x;
  int t = threadIdx.x;
  int y = t >> 5, x = t & 31;
  __shared__ float fin[2][1024];
  __shared__ float hb[2][1024];
  fin[0][t] = c_up[b * 1024 + t];
  fin[1][t] = f_map[b * 1024 + t];
  __syncthreads();
  for (int oc = 0; oc < 2; ++oc) {
    float a = fb1[oc];
    #pragma unroll
    for (int ic = 0; ic < 2; ++ic)
      #pragma unroll
      for (int ky = 0; ky < 3; ++ky)
        #pragma unroll
        for (int kx = 0; kx < 3; ++kx) {
          int yy = y + ky - 1, xx = x + kx - 1;
          float v = (yy >= 0 && yy < 32 && xx >= 0 && xx < 32)
                        ? fin[ic][yy * 32 + xx] : 0.f;
          a += v * fW1[((oc * 2 + ic) * 3 + ky) * 3 + kx];
        }
    hb[oc][t] = fmaxf(a, 0.f);
  }
  __syncthreads();
  float a = fb2[0];
  #pragma unroll
  for (int ic = 0; ic < 2; ++ic)
    #pragma unroll
    for (int ky = 0; ky < 3; ++ky)
      #pragma unroll
      for (int kx = 0; kx < 3; ++kx) {
        int yy = y + ky - 1, xx = x + kx - 1;
        float v = (yy >= 0 && yy < 32 && xx >= 0 && xx < 32)
                      ? hb[ic][yy * 32 + xx] : 0.f;
        a += v * fW2[(ic * 3 + ky) * 3 + kx];
      }
  outp[b * 1024 + t] = a;
}

extern "C" void kernel_launch(void* const* d_in, const int* in_sizes, int n_in,
                              void* d_out, int out_size, void* d_ws, size_t ws_size,
                              hipStream_t stream) {
  const float* x    = (const float*)d_in[0];
  const float* Wpc  = (const float*)d_in[1];
  const float* bpc  = (const float*)d_in[2];
  const float* Wpf  = (const float*)d_in[3];
  const float* bpf  = (const float*)d_in[4];
  const float* te   = (const float*)d_in[5];
  const float* ln1g = (const float*)d_in[6];
  const float* ln1b = (const float*)d_in[7];
  const float* Wqkv = (const float*)d_in[8];
  const float* Wo   = (const float*)d_in[9];
  const float* bo   = (const float*)d_in[10];
  const float* ln2g = (const float*)d_in[11];
  const float* ln2b = (const float*)d_in[12];
  const float* W1   = (const float*)d_in[13];
  const float* b1   = (const float*)d_in[14];
  const float* W2   = (const float*)d_in[15];
  const float* b2   = (const float*)d_in[16];
  const float* dWc  = (const float*)d_in[17];
  const float* dbc  = (const float*)d_in[18];
  const float* dWf  = (const float*)d_in[19];
  const float* dbf  = (const float*)d_in[20];
  const float* fW1  = (const float*)d_in[21];
  const float* fb1  = (const float*)d_in[22];
  const float* fW2  = (const float*)d_in[23];
  const float* fb2  = (const float*)d_in[24];

  char* ws = (char*)d_ws;
  float* tokens = (float*)ws;                 ws += 1310720 * 4;   // fp32 [B*N,128]
  float* fineb  = (float*)ws;                 ws += 1048576 * 4;   // fp32
  short* ybuf   = (short*)ws;                 ws += 1310720 * 2;   // bf16
  short* qkvb   = (short*)ws;                 ws += 3932160 * 2;   // bf16 [B*N,384]
  short* obuf   = (short*)ws;                 ws += 1310720 * 2;   // bf16
  short* hbuf   = (short*)ws;                 ws += 2621440 * 2;   // bf16 [B*N,256]
  short* WtQKV  = (short*)ws;                 ws += 98304 * 2;     // [L][384][128]
  short* WtO    = (short*)ws;                 ws += 32768 * 2;     // [L][128][128]
  short* Wt1    = (short*)ws;                 ws += 65536 * 2;     // [L][256][128]
  short* Wt2    = (short*)ws;                 ws += 65536 * 2;     // [L][128][256]
  float* msort  = (float*)ws;                 ws += 8192 * 4;
  float* c_up   = (float*)ws;                 ws += 8192 * 4;
  float* f_map  = (float*)ws;                 ws += 8192 * 4;
  int*   order  = (int*)ws;                   ws += 8192 * 4;

  const int M = Bx * NTOK;                    // 10240

  k_prep_w<<<1024, 256, 0, stream>>>(Wqkv, Wo, W1, W2, WtQKV, WtO, Wt1, Wt2);
  k_coarse<<<Bx * NCc, 128, 0, stream>>>(x, Wpc, bpc, te, tokens);
  k_fine<<<Bx * NFf, 128, 0, stream>>>(x, Wpf, bpf, fineb);
  k_edge_sort<<<Bx, 1024, 0, stream>>>(x, order, msort);
  k_fine_tokens<<<Bx * NFf, 128, 0, stream>>>(fineb, order, msort, te, tokens);

  for (int l = 0; l < LL; ++l) {
    k_ln_bf16<<<M / 4, 256, 0, stream>>>(tokens, ln1g + l * DD, ln1b + l * DD, ybuf);
    k_gemm_mfma<<<dim3(M / 64, 384 / 64), 256, 0, stream>>>(
        ybuf, WtQKV + (size_t)l * 49152, nullptr, nullptr, qkvb, 128, 384, 0);
    k_attn_mfma<<<Bx * HEADS * (NTOK / 64), 256, 0, stream>>>(qkvb, obuf);
    k_gemm_mfma<<<dim3(M / 64, 128 / 64), 256, 0, stream>>>(
        obuf, WtO + (size_t)l * 16384, bo + l * DD, tokens, nullptr, 128, 128, 0);
    k_ln_bf16<<<M / 4, 256, 0, stream>>>(tokens, ln2g + l * DD, ln2b + l * DD, ybuf);
    k_gemm_mfma<<<dim3(M / 64, 256 / 64), 256, 0, stream>>>(
        ybuf, Wt1 + (size_t)l * 32768, b1 + l * 256, nullptr, hbuf, 128, 256, 1);
    k_gemm_mfma<<<dim3(M / 64, 128 / 64), 256, 0, stream>>>(
        hbuf, Wt2 + (size_t)l * 32768, b2 + l * DD, tokens, nullptr, 256, 128, 0);
  }

  k_coarse_dec<<<Bx, 1024, 0, stream>>>(tokens, dWc, dbc, c_up);
  k_fine_dec<<<Bx * NFf / 256, 256, 0, stream>>>(tokens, dWf, dbf, msort, order, f_map);
  k_fuse_conv<<<Bx, 1024, 0, stream>>>(c_up, f_map, fW1, fb1, fW2, fb2, (float*)d_out);
}